// Round 1
// baseline (377.959 us; speedup 1.0000x reference)
//
#include <hip/hip_runtime.h>

namespace {
constexpr int NB = 1024;   // nodes
constexpr int NC = 128;    // channels
constexpr int NL = 16;     // coupling dim
constexpr int NE = 10;     // elements
constexpr int NOUT = 4 * NC;  // 512 output cols per node
constexpr int ROWPAD = 17;    // LDS row stride (conflict-free: 17 coprime to 32)
constexpr int CHUNK = 256;    // nodes staged per chunk
constexpr int NTHREADS = 256;
}

// One pass = one output irrep slice (0e, or 1o w-slice).
// Builds uw3[256 pairs][16], uw2[256], uw1[16] in LDS from U*, W*[e,:,c],
// then each wave processes nodes: out = sum_q x_i x_j (uw2[q] + sum_m uw3[q,m] x_m)
//                                     + sum_i uw1[i] x_i
template <int P3, int P2>
__device__ __forceinline__ void run_pass(
    const float* __restrict__ U3p,   // [4096, P3]  g = (i*16+j)*16+m
    const float* __restrict__ U2p,   // [256, P2]
    const float* __restrict__ U1p,   // [16]
    const float* __restrict__ W3p,   // W3[e,k,c], stride NC per k
    const float* __restrict__ W2p,   // W2[e,k,c], stride NC per k
    float w1,
    float* __restrict__ s_uw3, float* __restrict__ s_uw2, float* __restrict__ s_uw1,
    const float (* __restrict__ s_x)[NL], const int* __restrict__ s_nid, int cl,
    float* __restrict__ out, int out_off, int tid)
{
    // ---- build UW tiles in LDS (k-contraction amortized over all nodes of e) ----
    float w3r[P3];
#pragma unroll
    for (int k = 0; k < P3; ++k) w3r[k] = W3p[k * NC];

    for (int g = tid; g < 4096; g += NTHREADS) {
        const float* up = U3p + (size_t)g * P3;
        float s = 0.f;
#pragma unroll
        for (int k = 0; k < P3; ++k) s = fmaf(up[k], w3r[k], s);
        s_uw3[(g >> 4) * ROWPAD + (g & 15)] = s;
    }
    {
        const float* up = U2p + tid * P2;   // exactly one q per thread (256)
        float s = 0.f;
#pragma unroll
        for (int k = 0; k < P2; ++k) s = fmaf(up[k], W2p[k * NC], s);
        s_uw2[tid] = s;
    }
    if (tid < NL) s_uw1[tid] = U1p[tid] * w1;
    __syncthreads();

    // ---- per-lane register cache of 4 uw3 rows (read LDS once per pass) ----
    const int lane = tid & 63;
    const int wv = tid >> 6;
    float r3[4][NL];
    float r2[4];
#pragma unroll
    for (int a = 0; a < 4; ++a) {
        const int q = lane + 64 * a;
#pragma unroll
        for (int m = 0; m < NL; ++m) r3[a][m] = s_uw3[q * ROWPAD + m];
        r2[a] = s_uw2[q];
    }
    const float r1 = (lane < NL) ? s_uw1[lane] : 0.f;
    const int j = lane & 15;        // q = lane + 64a -> j = q&15 (fixed), i = (lane>>4)+4a
    const int ibase = lane >> 4;

    // ---- node loop: one node per wave, shuffle-reduce over 64 lanes ----
    for (int n = wv; n < cl; n += 4) {
        float xv[NL];
#pragma unroll
        for (int m = 0; m < NL; ++m) xv[m] = s_x[n][m];   // same-addr LDS broadcast
        const float xj = xv[j];
        float acc = (lane < NL) ? r1 * xv[lane] : 0.f;
#pragma unroll
        for (int a = 0; a < 4; ++a) {
            float s = r2[a];
#pragma unroll
            for (int m = 0; m < NL; ++m) s = fmaf(r3[a][m], xv[m], s);
            acc = fmaf(xj * xv[ibase + 4 * a], s, acc);
        }
#pragma unroll
        for (int off = 32; off > 0; off >>= 1) acc += __shfl_xor(acc, off, 64);
        if (lane == 0) out[(size_t)s_nid[n] * NOUT + out_off] = acc;
    }
    __syncthreads();   // uw3 buffer free for next pass
}

__global__ void __launch_bounds__(NTHREADS, 2) symcon_kernel(
    const float* __restrict__ x, const float* __restrict__ y,
    const float* __restrict__ U1_0e, const float* __restrict__ U2_0e,
    const float* __restrict__ U3_0e,
    const float* __restrict__ W1_0e, const float* __restrict__ W2_0e,
    const float* __restrict__ W3_0e,
    const float* __restrict__ U1_1o, const float* __restrict__ U2_1o,
    const float* __restrict__ U3_1o,
    const float* __restrict__ W1_1o, const float* __restrict__ W2_1o,
    const float* __restrict__ W3_1o,
    float* __restrict__ out)
{
    __shared__ float s_uw3[256 * ROWPAD];   // 17 KiB
    __shared__ float s_uw2[256];
    __shared__ float s_uw1[NL];
    __shared__ int   s_nid[NB];             // 4 KiB
    __shared__ int   s_cnt;
    __shared__ float s_x[CHUNK][NL];        // 16 KiB

    const int tid = threadIdx.x;
    const int bid = blockIdx.x;
    const int e = bid % NE;
    const int c = bid / NE;

    // ---- gather nodes of element e (one-hot y) ----
    if (tid == 0) s_cnt = 0;
    __syncthreads();
    for (int b = tid; b < NB; b += NTHREADS) {
        if (y[b * NE + e] > 0.5f) {
            int i = atomicAdd(&s_cnt, 1);
            s_nid[i] = b;
        }
    }
    __syncthreads();
    const int nn = s_cnt;
    if (nn == 0) return;

    const float w1_0 = W1_0e[e * NC + c];
    const float w1_1 = W1_1o[e * NC + c];

    for (int cs = 0; cs < nn; cs += CHUNK) {
        const int cl = min(CHUNK, nn - cs);
        // stage x[b, c, :] for this chunk's nodes
        if (tid < cl) {
            const int b = s_nid[cs + tid];
            const float4* xp = reinterpret_cast<const float4*>(x + ((size_t)b * NC + c) * NL);
            float4* sp = reinterpret_cast<float4*>(&s_x[tid][0]);
            sp[0] = xp[0]; sp[1] = xp[1]; sp[2] = xp[2]; sp[3] = xp[3];
        }
        __syncthreads();

        // pass 0e -> out[:, c]
        run_pass<23, 4>(U3_0e, U2_0e, U1_0e,
                        W3_0e + (size_t)e * 23 * NC + c,
                        W2_0e + (size_t)e * 4 * NC + c, w1_0,
                        s_uw3, s_uw2, s_uw1, s_x, s_nid + cs, cl, out, c, tid);
        // passes 1o w=0..2 -> out[:, 128 + 3c + w]
        for (int w = 0; w < 3; ++w) {
            run_pass<37, 6>(U3_1o + (size_t)w * 4096 * 37,
                            U2_1o + w * 256 * 6,
                            U1_1o + w * NL,
                            W3_1o + (size_t)e * 37 * NC + c,
                            W2_1o + (size_t)e * 6 * NC + c, w1_1,
                            s_uw3, s_uw2, s_uw1, s_x, s_nid + cs, cl, out,
                            NC + c * 3 + w, tid);
        }
    }
}

extern "C" void kernel_launch(void* const* d_in, const int* in_sizes, int n_in,
                              void* d_out, int out_size, void* d_ws, size_t ws_size,
                              hipStream_t stream) {
    const float* x     = (const float*)d_in[0];
    const float* y     = (const float*)d_in[1];
    const float* U1_0e = (const float*)d_in[2];
    const float* U2_0e = (const float*)d_in[3];
    const float* U3_0e = (const float*)d_in[4];
    const float* W1_0e = (const float*)d_in[5];
    const float* W2_0e = (const float*)d_in[6];
    const float* W3_0e = (const float*)d_in[7];
    const float* U1_1o = (const float*)d_in[8];
    const float* U2_1o = (const float*)d_in[9];
    const float* U3_1o = (const float*)d_in[10];
    const float* W1_1o = (const float*)d_in[11];
    const float* W2_1o = (const float*)d_in[12];
    const float* W3_1o = (const float*)d_in[13];
    float* out = (float*)d_out;

    hipLaunchKernelGGL(symcon_kernel, dim3(NE * NC), dim3(NTHREADS), 0, stream,
                       x, y, U1_0e, U2_0e, U3_0e, W1_0e, W2_0e, W3_0e,
                       U1_1o, U2_1o, U3_1o, W1_1o, W2_1o, W3_1o, out);
}